// Round 1
// baseline (28.823 us; speedup 1.0000x reference)
//
#include <hip/hip_runtime.h>

// StablePolicy3phase: out[b,:] = sum_h softthresh(s[b]·W[h], bn[h]) + 0.001*s[b]
//   s   = clip(state-1.03,0,inf) - clip(0.97-state,0,inf)
//   W[h] = sum_k lambda[h,k]^2 * E_k  (symmetric 3x3, 6 unique elems)
//   bn  = 0.15 * clip(b,0) / sum(clip(b,0))     (global scalar sum)
//   softthresh(x,t) = relu(x-t) - relu(-x-t) = copysign(max(|x|-t,0), x)

#define VMAX_T 1.03f   // VMAX - 0.02
#define VMIN_T 0.97f   // VMIN + 0.02
#define SCALE_C 0.15f

constexpr int HMAX = 256;

__global__ __launch_bounds__(256) void policy_kernel(
    const float* __restrict__ state,
    const float* __restrict__ bvec,
    const float* __restrict__ lam,
    float* __restrict__ out,
    int B, int H)
{
    // Per-head table: 3 float4 per head = {w00,w01,w02,w11},{w12,w22,bn0,bn1},{bn2,0,0,0}
    __shared__ float4 tbl[HMAX * 3];
    __shared__ float wsum[4];

    const int tid = threadIdx.x;

    // ---- Stage 1 (block-redundant, ~1us): global sum S = sum clip(b,0) ----
    float p = 0.f;
    if (tid < H) {
        p = fmaxf(bvec[tid * 3 + 0], 0.f)
          + fmaxf(bvec[tid * 3 + 1], 0.f)
          + fmaxf(bvec[tid * 3 + 2], 0.f);
    }
    #pragma unroll
    for (int off = 32; off > 0; off >>= 1)
        p += __shfl_down(p, off, 64);
    if ((tid & 63) == 0) wsum[tid >> 6] = p;
    __syncthreads();
    const float S = wsum[0] + wsum[1] + wsum[2] + wsum[3];
    const float inv = SCALE_C / S;

    // ---- Stage 2: per-head W (6 unique symmetric elems) + bn into LDS ----
    if (tid < H) {
        float l0 = lam[tid * 6 + 0]; l0 *= l0;
        float l1 = lam[tid * 6 + 1]; l1 *= l1;
        float l2 = lam[tid * 6 + 2]; l2 *= l2;
        float l3 = lam[tid * 6 + 3]; l3 *= l3;
        float l4 = lam[tid * 6 + 4]; l4 *= l4;
        float l5 = lam[tid * 6 + 5]; l5 *= l5;
        // E order: (0,0),(1,0),(1,1),(2,0),(2,1),(2,2)
        float w00 = l0 + l1 + l3;
        float w11 = l1 + l2 + l4;
        float w22 = l3 + l4 + l5;
        float w01 = -l1;
        float w02 = -l3;
        float w12 = -l4;
        float bn0 = fmaxf(bvec[tid * 3 + 0], 0.f) * inv;
        float bn1 = fmaxf(bvec[tid * 3 + 1], 0.f) * inv;
        float bn2 = fmaxf(bvec[tid * 3 + 2], 0.f) * inv;
        tbl[tid * 3 + 0] = make_float4(w00, w01, w02, w11);
        tbl[tid * 3 + 1] = make_float4(w12, w22, bn0, bn1);
        tbl[tid * 3 + 2] = make_float4(bn2, 0.f, 0.f, 0.f);
    }
    __syncthreads();

    // ---- Stage 3: one output row per thread ----
    const int r = blockIdx.x * blockDim.x + tid;
    if (r >= B) return;

    const float x0 = state[r * 3 + 0];
    const float x1 = state[r * 3 + 1];
    const float x2 = state[r * 3 + 2];
    const float s0 = fmaxf(x0 - VMAX_T, 0.f) - fmaxf(VMIN_T - x0, 0.f);
    const float s1 = fmaxf(x1 - VMAX_T, 0.f) - fmaxf(VMIN_T - x1, 0.f);
    const float s2 = fmaxf(x2 - VMAX_T, 0.f) - fmaxf(VMIN_T - x2, 0.f);

    float a0 = 0.f, a1 = 0.f, a2 = 0.f;

    #pragma unroll 4
    for (int h = 0; h < H; ++h) {
        // wave-uniform LDS reads -> broadcast, conflict-free
        const float4 wa = tbl[h * 3 + 0];  // w00 w01 w02 w11
        const float4 wb = tbl[h * 3 + 1];  // w12 w22 bn0 bn1
        const float4 wc = tbl[h * 3 + 2];  // bn2 - - -

        const float v0 = s0 * wa.x + s1 * wa.y + s2 * wa.z;
        const float v1 = s0 * wa.y + s1 * wa.w + s2 * wb.x;
        const float v2 = s0 * wa.z + s1 * wb.x + s2 * wb.y;

        const float d0 = fmaxf(fabsf(v0) - wb.z, 0.f);
        const float d1 = fmaxf(fabsf(v1) - wb.w, 0.f);
        const float d2 = fmaxf(fabsf(v2) - wc.x, 0.f);

        a0 += copysignf(d0, v0);
        a1 += copysignf(d1, v1);
        a2 += copysignf(d2, v2);
    }

    out[r * 3 + 0] = a0 + 0.001f * s0;
    out[r * 3 + 1] = a1 + 0.001f * s1;
    out[r * 3 + 2] = a2 + 0.001f * s2;
}

extern "C" void kernel_launch(void* const* d_in, const int* in_sizes, int n_in,
                              void* d_out, int out_size, void* d_ws, size_t ws_size,
                              hipStream_t stream) {
    const float* state = (const float*)d_in[0];
    const float* bvec  = (const float*)d_in[1];
    const float* lam   = (const float*)d_in[2];
    float* out = (float*)d_out;

    const int B = in_sizes[0] / 3;
    const int H = in_sizes[1] / 3;   // 256

    const int block = 256;
    const int grid = (B + block - 1) / block;
    hipLaunchKernelGGL(policy_kernel, dim3(grid), dim3(block), 0, stream,
                       state, bvec, lam, out, B, H);
}